// Round 18
// baseline (475.073 us; speedup 1.0000x reference)
//
#include <hip/hip_runtime.h>
#include <cstdio>

typedef unsigned short u16;
typedef __bf16 bf16x8 __attribute__((ext_vector_type(8)));
typedef float f32x4 __attribute__((ext_vector_type(4)));
typedef unsigned short us4 __attribute__((ext_vector_type(4)));
typedef unsigned short us8 __attribute__((ext_vector_type(8)));

__device__ __forceinline__ u16 f2bf(float f) {
    union { float f; unsigned u; } x; x.f = f;
    unsigned u = x.u + 0x7fffu + ((x.u >> 16) & 1u);   // RNE
    return (u16)(u >> 16);
}
__device__ __forceinline__ float bf2f(u16 u) {
    union { unsigned u; float f; } x; x.u = ((unsigned)u) << 16;
    return x.f;
}

// ---------------------------------------------------------------------------
// NT GEMM: C[M,N] = A[M,K] * B[N,K]^T, bf16 in, fp32 accumulate.
// 256x256 tile, BK=64, 512 threads (8 waves 2Mx4N, 128x64 per wave).
// R16 kernel, VERIFIED at 473.17 us / absmax 0.03125 — final form.
// Per-phase half-tile staging + derived per-phase counted vmcnt:
//   p1: reads af0(8)+bfr0(4) ; stage Ah0(T+1) ; BAR ; lgkm0 ; Q00 ; vm(4) ; BAR
//   p2: reads bfr1(4)        ; stage Bh0(T+1) ; BAR ; lgkm0 ; Q01 ; vm(4) ; BAR
//   p3: reads af1(8)         ; stage Bh1(T+1) ; BAR ; lgkm0 ; Q10 ;         BAR
//   p4:                        stage Ah1(T+1) ;               Q11 ; vm(4) ; BAR
// Tail tile: vm(2) after p1, vm(0) after p2. Waits sit after the MFMA
// cluster, before the trailing barrier (wait+barrier = cross-wave RAW).
// WAR: stage target (buf d^1, half h) last ds_read >= 5 barriers earlier.
// LDS: 2 bufs x 2 half-slots of 16 KB per operand; A half = (d*2+wr),
// B half = (d*2 + wc>>1), local B row base (wc&1)*64. XOR-swizzled rows
// (phys_koff = koff ^ (((row)&7)<<4)); stage pre-swizzles the GLOBAL source
// (both-sides rule). Bank conflicts = 0 (R12-R16 verified).
// EMIT_VT (G2 only): epilogue additionally writes V^T[b][n][s].
// grid: (N/256, M/256, batch) flattened; nwg % 8 == 0 for the XCD remap.
// ---------------------------------------------------------------------------

#define LDFRAG(base, row, koff) \
  (*(const bf16x8*)((const char*)(base) + (size_t)(row) * 128 + \
                    ((koff) ^ (((row) & 7) << 4))))

#define BAR() do { \
  asm volatile("" ::: "memory"); \
  __builtin_amdgcn_s_barrier(); \
  asm volatile("" ::: "memory"); \
} while (0)

#define LGKM0() asm volatile("s_waitcnt lgkmcnt(0)" ::: "memory")
#define VMC4()  asm volatile("s_waitcnt vmcnt(4)" ::: "memory")
#define VMC2()  asm volatile("s_waitcnt vmcnt(2)" ::: "memory")
#define VMC0()  asm volatile("s_waitcnt vmcnt(0)" ::: "memory")

#define MFMA16(AF, BF, MO, NO) do { \
  __builtin_amdgcn_s_setprio(1); \
  _Pragma("unroll") for (int j = 0; j < 4; ++j) \
    _Pragma("unroll") for (int i = 0; i < 2; ++i) \
      _Pragma("unroll") for (int ks = 0; ks < 2; ++ks) \
        acc[(MO) + j][(NO) + i] = __builtin_amdgcn_mfma_f32_16x16x32_bf16( \
            AF[j][ks], BF[i][ks], acc[(MO) + j][(NO) + i], 0, 0, 0); \
  __builtin_amdgcn_s_setprio(0); \
} while (0)

template<int TAG, bool HAS_BIAS, bool HAS_RESID, bool OUT_BF16, bool EMIT_VT>
__global__ __launch_bounds__(512, 2)
void gemm_nt(const u16* __restrict__ A, const u16* __restrict__ Bm,
             void* __restrict__ Cm, const float* __restrict__ bias,
             const float* __restrict__ resid, u16* __restrict__ vt,
             int K, int lda, int ldb, int ldc,
             long sA, long sB, long sC, float scale)
{
    // 2 buffers x 2 half-slots per operand, 8192 u16 (16 KB) each.
    __shared__ __align__(16) u16 lA[4 * 128 * 64];   // 64 KiB
    __shared__ __align__(16) u16 lB[4 * 128 * 64];   // 64 KiB

    const int tid = threadIdx.x;

    // ---- bijective XCD chunking over the flattened 3D grid (nwg%8==0) ----
    const int gx = gridDim.x, gy = gridDim.y;
    int flat = ((int)blockIdx.z * gy + blockIdx.y) * gx + blockIdx.x;
    const int nwg = gx * gy * (int)gridDim.z;
    const int q = nwg >> 3;
    flat = (flat & 7) * q + (flat >> 3);
    const int bx = flat % gx;
    const int t2 = flat / gx;
    const int by = t2 % gy;
    const long bz = t2 / gy;

    A  += bz * sA;
    Bm += bz * sB;
    const long cbase = bz * sC;
    const int m0 = by * 256;
    const int n0 = bx * 256;

    const int lane = tid & 63;
    const int w  = tid >> 6;                  // wave 0..7
    const int wr = w >> 2, wc = w & 3;        // 2x4 wave grid, 128x64 per wave
    const int fr = lane & 15;                 // A row / B col within fragment
    const int kg = lane >> 4;                 // k-group (0..3)

    // stage one half-tile (128 rows x 64 K = 16 KB) of operand op, half h,
    // K-tile kt, into buf (kt&1) half h. Global source pre-swizzled;
    // LDS dest linear. 2 global_load_lds per thread per call.
    auto stage_half = [&](int kt, int op, int h) {
        const u16* src = op ? Bm : A;
        const int  ld  = op ? ldb : lda;
        const int  bs  = op ? n0 : m0;
        u16* lds = (op ? lB : lA) + (size_t)((kt & 1) * 2 + h) * 8192;
#pragma unroll
        for (int i2 = 0; i2 < 2; ++i2) {
            const int c  = i2 * 512 + tid;            // 16B chunk id, 0..1023
            const int r  = c >> 3;                    // row within half
            const int kb = ((c & 7) * 16) ^ ((r & 7) << 4);   // pre-swizzled k byte
            const u16* g = src + (size_t)(bs + h * 128 + r) * ld + kt * 64 + (kb >> 1);
            __builtin_amdgcn_global_load_lds(
                (const __attribute__((address_space(1))) void*)g,
                (__attribute__((address_space(3))) void*)(lds + (size_t)c * 8), 16, 0, 0);
        }
    };

    f32x4 acc[8][4] = {};

    const int nt = K >> 6;                    // nt >= 12 for all GEMMs here
    // prologue: tile 0's halves in consumption order (Ah0, Bh0, Bh1, Ah1)
    stage_half(0, 0, 0); stage_half(0, 1, 0);
    stage_half(0, 1, 1); stage_half(0, 0, 1);
    VMC4();                                   // Ah0(0), Bh0(0) landed
    BAR();

    const int bRowBase = (wc & 1) * 64;       // B local row base within half

    for (int T = 0; T < nt; ++T) {
        const int d = T & 1;
        const u16* pA = lA + (size_t)(d * 2 + wr) * 8192;        // wave's A half
        const u16* pB = lB + (size_t)(d * 2 + (wc >> 1)) * 8192; // wave's B half
        const bool pre = (T + 1 < nt);

        bf16x8 af0[4][2], af1[4][2], bfr0[2][2], bfr1[2][2];

        // ---- phase 1: read af0 (local rows 0-63) + bfr0 ; stage Ah0(T+1) ; Q00
#pragma unroll
        for (int j = 0; j < 4; ++j)
#pragma unroll
            for (int ks = 0; ks < 2; ++ks)
                af0[j][ks] = LDFRAG(pA, j * 16 + fr, ks * 64 + kg * 16);
#pragma unroll
        for (int i = 0; i < 2; ++i)
#pragma unroll
            for (int ks = 0; ks < 2; ++ks)
                bfr0[i][ks] = LDFRAG(pB, bRowBase + i * 16 + fr, ks * 64 + kg * 16);
        if (pre) stage_half(T + 1, 0, 0);
        BAR();
        LGKM0();
        MFMA16(af0, bfr0, 0, 0);
        if (pre) VMC4(); else VMC2();         // guards p2's Bh1(T) read
        BAR();

        // ---- phase 2: read bfr1 ; stage Bh0(T+1) ; Q01 ----
#pragma unroll
        for (int i = 0; i < 2; ++i)
#pragma unroll
            for (int ks = 0; ks < 2; ++ks)
                bfr1[i][ks] = LDFRAG(pB, bRowBase + 32 + i * 16 + fr, ks * 64 + kg * 16);
        if (pre) stage_half(T + 1, 1, 0);
        BAR();
        LGKM0();
        MFMA16(af0, bfr1, 0, 2);
        if (pre) VMC4(); else VMC0();         // guards p3's Ah1(T) read
        BAR();

        // ---- phase 3: read af1 (local rows 64-127) ; stage Bh1(T+1) ; Q10
#pragma unroll
        for (int j = 0; j < 4; ++j)
#pragma unroll
            for (int ks = 0; ks < 2; ++ks)
                af1[j][ks] = LDFRAG(pA, 64 + j * 16 + fr, ks * 64 + kg * 16);
        if (pre) stage_half(T + 1, 1, 1);
        BAR();
        LGKM0();
        MFMA16(af1, bfr0, 4, 0);
        BAR();                                // p4 is register-only: no vmcnt

        // ---- phase 4: stage Ah1(T+1) ; Q11 (register-only MFMA) ----
        if (pre) stage_half(T + 1, 0, 1);
        MFMA16(af1, bfr1, 4, 2);
        if (pre) VMC4();                      // guards next p1's Ah0/Bh0 reads
        BAR();
    }

    // epilogue: C/D layout col=lane&15, row=(lane>>4)*4+reg  [m89-verified]
    const int orow = m0 + wr * 128 + kg * 4;
    const int ocol = n0 + wc * 64 + fr;
#pragma unroll
    for (int mf = 0; mf < 8; ++mf) {
        const int mbase = orow + mf * 16;     // 4 consecutive rows mbase..+3
#pragma unroll
        for (int nf = 0; nf < 4; ++nf) {
            const int n = ocol + nf * 16;
            float v4[4];
#pragma unroll
            for (int r = 0; r < 4; ++r) {
                const int m = mbase + r;
                float v = acc[mf][nf][r] * scale;
                if (HAS_BIAS)  v += bias[n];
                if (HAS_RESID) v += resid[cbase + (long)m * ldc + n];
                v4[r] = v;
                if (OUT_BF16)  ((u16*)Cm)[cbase + (long)m * ldc + n] = f2bf(v);
                else           ((float*)Cm)[cbase + (long)m * ldc + n] = v;
            }
            if (EMIT_VT) {
                // rows m = b*2048 + s; write Vt[b][n][s..s+3] (batch S=2048)
                const long b_ = mbase >> 11;
                const int  s  = mbase & 2047;
                us4 o;
#pragma unroll
                for (int r = 0; r < 4; ++r) o[r] = f2bf(v4[r]);
                *(us4*)(vt + (b_ * 1024 + n) * 2048 + s) = o;
            }
        }
    }
}

// ---------------------------------------------------------------------------
// LayerNorm over D=1024, one block (256 thr) per row.
// ---------------------------------------------------------------------------
template<bool IN_BF16, bool OUT_BF16>
__global__ __launch_bounds__(256)
void ln1024(const void* in, const float* __restrict__ g,
            const float* __restrict__ beta, void* out)
{
    const long row = blockIdx.x;
    const int tid = threadIdx.x;
    float x0, x1, x2, x3;
    if (IN_BF16) {
        const us4 v = ((const us4*)in)[row * 256 + tid];
        x0 = bf2f(v[0]); x1 = bf2f(v[1]); x2 = bf2f(v[2]); x3 = bf2f(v[3]);
    } else {
        const float4 v = ((const float4*)in)[row * 256 + tid];
        x0 = v.x; x1 = v.y; x2 = v.z; x3 = v.w;
    }
    float s  = x0 + x1 + x2 + x3;
    float s2 = x0 * x0 + x1 * x1 + x2 * x2 + x3 * x3;
#pragma unroll
    for (int off = 32; off > 0; off >>= 1) {
        s  += __shfl_xor(s, off);
        s2 += __shfl_xor(s2, off);
    }
    __shared__ float rs[4], rq[4];
    if ((tid & 63) == 0) { rs[tid >> 6] = s; rq[tid >> 6] = s2; }
    __syncthreads();
    const float S  = rs[0] + rs[1] + rs[2] + rs[3];
    const float S2 = rq[0] + rq[1] + rq[2] + rq[3];
    const float mu = S * (1.0f / 1024.0f);
    const float var = S2 * (1.0f / 1024.0f) - mu * mu;
    const float rstd = rsqrtf(var + 1e-5f);
    const float4 gg = ((const float4*)g)[tid];
    const float4 bb = ((const float4*)beta)[tid];
    const float y0 = (x0 - mu) * rstd * gg.x + bb.x;
    const float y1 = (x1 - mu) * rstd * gg.y + bb.y;
    const float y2 = (x2 - mu) * rstd * gg.z + bb.z;
    const float y3 = (x3 - mu) * rstd * gg.w + bb.w;
    if (OUT_BF16) {
        us4 o; o[0] = f2bf(y0); o[1] = f2bf(y1); o[2] = f2bf(y2); o[3] = f2bf(y3);
        ((us4*)out)[row * 256 + tid] = o;
    } else {
        float4 o; o.x = y0; o.y = y1; o.z = y2; o.w = y3;
        ((float4*)out)[row * 256 + tid] = o;
    }
}

// ---------------------------------------------------------------------------
// Softmax over width 2048, bf16 in/out, IN-PLACE. One block per row.
// ---------------------------------------------------------------------------
__global__ __launch_bounds__(256)
void softmax2048_bf16(u16* io)
{
    const long row = blockIdx.x;
    const int tid = threadIdx.x;
    const us8 v = ((const us8*)io)[row * 256 + tid];
    float x[8];
#pragma unroll
    for (int i = 0; i < 8; ++i) x[i] = bf2f(v[i]);
    float m = x[0];
#pragma unroll
    for (int i = 1; i < 8; ++i) m = fmaxf(m, x[i]);
#pragma unroll
    for (int off = 32; off > 0; off >>= 1) m = fmaxf(m, __shfl_xor(m, off));
    __shared__ float rm[4], rsum[4];
    if ((tid & 63) == 0) rm[tid >> 6] = m;
    __syncthreads();
    m = fmaxf(fmaxf(rm[0], rm[1]), fmaxf(rm[2], rm[3]));
    float e[8];
    float s = 0.f;
#pragma unroll
    for (int i = 0; i < 8; ++i) { e[i] = __expf(x[i] - m); s += e[i]; }
#pragma unroll
    for (int off = 32; off > 0; off >>= 1) s += __shfl_xor(s, off);
    if ((tid & 63) == 0) rsum[tid >> 6] = s;
    __syncthreads();
    s = rsum[0] + rsum[1] + rsum[2] + rsum[3];
    const float inv = 1.0f / s;
    us8 o;
#pragma unroll
    for (int i = 0; i < 8; ++i) o[i] = f2bf(e[i] * inv);
    ((us8*)io)[row * 256 + tid] = o;
}

// ---------------------------------------------------------------------------
// Merged input cast: fp32 -> bf16, 8 elems/thread, two sources in one grid.
// ---------------------------------------------------------------------------
__global__ __launch_bounds__(256)
void cast2_f32_bf16(const float* __restrict__ srcA, u16* __restrict__ dstA, long nA8,
                    const float* __restrict__ srcB, u16* __restrict__ dstB, long nB8)
{
    long i = (long)blockIdx.x * 256 + threadIdx.x;
    const float* in;
    u16* out;
    if (i < nA8) { in = srcA; out = dstA; }
    else         { i -= nA8; if (i >= nB8) return; in = srcB; out = dstB; }
    const float4 a = ((const float4*)in)[i * 2];
    const float4 b = ((const float4*)in)[i * 2 + 1];
    us8 o;
    o[0] = f2bf(a.x); o[1] = f2bf(a.y); o[2] = f2bf(a.z); o[3] = f2bf(a.w);
    o[4] = f2bf(b.x); o[5] = f2bf(b.y); o[6] = f2bf(b.z); o[7] = f2bf(b.w);
    ((us8*)out)[i] = o;
}

// ---------------------------------------------------------------------------
// Merged weight transpose+cast: fp32 [R,C] -> bf16 [C,R], 3 weights in one
// grid (z selects descriptor; row-guard for z==1 R=768). block (32,8).
// ---------------------------------------------------------------------------
__global__ __launch_bounds__(256)
void tcast3_f32_bf16(const float* __restrict__ w0, u16* __restrict__ t0,
                     const float* __restrict__ w1, u16* __restrict__ t1,
                     const float* __restrict__ w2, u16* __restrict__ t2)
{
    const int z = blockIdx.z;
    const float* in; u16* out; int R;
    if      (z == 0) { in = w0; out = t0; R = 1024; }
    else if (z == 1) { in = w1; out = t1; R = 768;  }
    else             { in = w2; out = t2; R = 1024; }
    const int C = 1024;
    const int r0 = blockIdx.y * 32;
    if (r0 >= R) return;
    __shared__ float t[32][33];
    const int tx = threadIdx.x, ty = threadIdx.y;
    const int c0 = blockIdx.x * 32;
#pragma unroll
    for (int i = 0; i < 4; ++i)
        t[ty + i * 8][tx] = in[(long)(r0 + ty + i * 8) * C + c0 + tx];
    __syncthreads();
#pragma unroll
    for (int i = 0; i < 4; ++i)
        out[(long)(c0 + ty + i * 8) * R + r0 + tx] = f2bf(t[tx][ty + i * 8]);
}

// ---------------------------------------------------------------------------
extern "C" void kernel_launch(void* const* d_in, const int* in_sizes, int n_in,
                              void* d_out, int out_size, void* d_ws, size_t ws_size,
                              hipStream_t stream)
{
    const float* H_l      = (const float*)d_in[0];
    const float* H_a      = (const float*)d_in[1];
    const float* W_text   = (const float*)d_in[2];
    const float* b_text   = (const float*)d_in[3];
    const float* W_audio  = (const float*)d_in[4];
    const float* b_audio  = (const float*)d_in[5];
    const float* W_out    = (const float*)d_in[6];
    const float* b_out    = (const float*)d_in[7];
    const float* g1       = (const float*)d_in[8];
    const float* beta1    = (const float*)d_in[9];
    const float* g2       = (const float*)d_in[10];
    const float* beta2    = (const float*)d_in[11];
    const float* g_out    = (const float*)d_in[12];
    const float* beta_out = (const float*)d_in[13];
    (void)in_sizes; (void)n_in; (void)out_size;

    const int B = 16, L = 1024, S = 2048, DT = 1024, DA = 768, H = 1024;

    // ---------------- workspace layout (~245.5 MiB, heavy overlay) ---------
    char* ws = (char*)d_ws;
    const size_t SZ_HLB = (size_t)B * L * DT * 2;
    const size_t SZ_HAB = (size_t)B * S * DA * 2;
    const size_t O_A    = SZ_HLB + SZ_HAB;
    const size_t SZ_A   = (size_t)B * L * H * 2;
    const size_t O_C    = O_A + SZ_A;
    const size_t SZ_C   = (size_t)B * S * H * 2;
    const size_t O_D    = O_C + SZ_C;
    const size_t SZ_D   = (size_t)B * S * H * 2;
    const size_t O_W    = O_D + SZ_D;
    const size_t need   = O_W + (size_t)(DT * H + DA * H + H * H) * 2;

    if (ws_size < need) {
        fprintf(stderr, "[kernel_launch] ws_size=%zu < needed=%zu — aborting launches\n",
                ws_size, need);
        return;
    }

    u16*   Hlb     = (u16*)(ws);
    u16*   Hab     = (u16*)(ws + SZ_HLB);
    u16*   Scores  = (u16*)(ws);                 // overlays Hlb/Hab after G2
    u16*   Abuf    = (u16*)(ws + O_A);           // text_p -> Q -> Hh
    u16*   Vbuf    = (u16*)(ws + O_C);           // audio_p (LN2 input)
    u16*   Kbuf    = (u16*)(ws + O_D);           // K
    u16*   OutPre  = (u16*)(ws + O_D);           // out_pre bf16 (after K dies)
    u16*   Wt_text  = (u16*)(ws + O_W);
    u16*   Wt_audio = Wt_text + (size_t)DT * H;
    u16*   Wt_out   = Wt_audio + (size_t)DA * H;
    u16*   Vt      = (u16*)d_out;                // dies before final LN

    const float scale = 0.03125f; // 1/sqrt(1024)

    // merged input casts to bf16 (one dispatch)
    const long nHl8 = (long)B * L * DT / 8;
    const long nHa8 = (long)B * S * DA / 8;
    cast2_f32_bf16<<<(unsigned)((nHl8 + nHa8 + 255) / 256), 256, 0, stream>>>(
        H_l, Hlb, nHl8, H_a, Hab, nHa8);
    // merged weight transposes [K,N] -> [N,K] bf16 (one dispatch)
    tcast3_f32_bf16<<<dim3(H / 32, 32, 3), dim3(32, 8), 0, stream>>>(
        W_text, Wt_text, W_audio, Wt_audio, W_out, Wt_out);

    // G1: text_p = H_l @ W_text + b_text   [16384,1024] bf16
    gemm_nt<1, true, false, true, false><<<dim3(H / 256, B * L / 256, 1), 512, 0, stream>>>(
        Hlb, Wt_text, Abuf, b_text, nullptr, nullptr, DT, DT, DT, H, 0, 0, 0, 1.0f);
    // LN1 in-place: text_p -> Q
    ln1024<true, true><<<B * L, 256, 0, stream>>>(Abuf, g1, beta1, Abuf);

    // G2: audio_p = H_a @ W_audio + b_audio [32768,1024] bf16 (= V),
    //     epilogue also writes V^T into Vt (d_out) -> no transpose kernel
    gemm_nt<2, true, false, true, true><<<dim3(H / 256, B * S / 256, 1), 512, 0, stream>>>(
        Hab, Wt_audio, Vbuf, b_audio, nullptr, Vt, DA, DA, DA, H, 0, 0, 0, 1.0f);
    // LN2: audio_p -> K
    ln1024<true, true><<<B * S, 256, 0, stream>>>(Vbuf, g2, beta2, Kbuf);

    // G3: scores = Q @ K^T * scale          [B,1024,2048] bf16
    gemm_nt<3, false, false, true, false><<<dim3(S / 256, L / 256, B), 512, 0, stream>>>(
        Abuf, Kbuf, Scores, nullptr, nullptr, nullptr, H, H, H, S,
        (long)L * H, (long)S * H, (long)L * S, scale);

    // softmax in-place on bf16 scores -> alpha
    softmax2048_bf16<<<B * L, 256, 0, stream>>>(Scores);

    // G5: H_hyper = alpha @ V (NT vs Vt)    [B,1024,1024] bf16 -> Abuf (Q dead)
    gemm_nt<5, false, false, true, false><<<dim3(H / 256, L / 256, B), 512, 0, stream>>>(
        Scores, Vt, Abuf, nullptr, nullptr, nullptr, S, S, S, H,
        (long)L * S, (long)H * S, (long)L * H, 1.0f);

    // G6: out_pre = H_hyper @ W_out + b_out + H_l  [16384,1024] bf16 (K dead)
    gemm_nt<6, true, true, true, false><<<dim3(H / 256, B * L / 256, 1), 512, 0, stream>>>(
        Abuf, Wt_out, OutPre, b_out, H_l, nullptr, H, H, H, H, 0, 0, 0, 1.0f);

    // LN3 (bf16 in) -> d_out fp32 (Vt dead)
    ln1024<true, false><<<B * L, 256, 0, stream>>>(OutPre, g_out, beta_out, (float*)d_out);
}